// Round 1
// baseline (109.439 us; speedup 1.0000x reference)
//
#include <hip/hip_runtime.h>

#define BB 2
#define NN 256
#define MMM 256
#define CC 256
#define HH 4
#define HCC 64

// ---------------------------------------------------------------------------
// K1: fused q/k/v projections.  rows 0..511 = q (B*N), 512..1023 = k, 1024..1535 = v
// out[row][j] = sum_k A[row][k] * W[k][j] + b[j]
// ---------------------------------------------------------------------------
__global__ __launch_bounds__(256) void proj_gemm(
    const float* __restrict__ q_tok, const float* __restrict__ k_tok, const float* __restrict__ v_tok,
    const float* __restrict__ Wq, const float* __restrict__ bq,
    const float* __restrict__ Wk, const float* __restrict__ bk,
    const float* __restrict__ Wv, const float* __restrict__ bv,
    float* __restrict__ out)
{
    const int row0 = blockIdx.x * 64;
    const int col0 = blockIdx.y * 64;
    const int seg  = row0 >> 9;            // 512-row segments
    const float* A    = seg == 0 ? q_tok : (seg == 1 ? k_tok : v_tok);
    const float* W    = seg == 0 ? Wq    : (seg == 1 ? Wk    : Wv);
    const float* bias = seg == 0 ? bq    : (seg == 1 ? bk    : bv);
    const int ar0 = row0 & 511;

    __shared__ float As[64][17];
    __shared__ float Bs[16][68];
    const int t  = threadIdx.x;
    const int tr = t >> 4, tc = t & 15;
    float acc[4][4] = {};

    const int sr  = t >> 2, sk4 = (t & 3) << 2;   // A-stage: row, k-offset
    const int bkr = t >> 4, bj4 = (t & 15) << 2;  // B-stage: k-row, j-offset

    for (int k0 = 0; k0 < 256; k0 += 16) {
        float4 a4 = *reinterpret_cast<const float4*>(&A[(ar0 + sr) * 256 + k0 + sk4]);
        float4 b4 = *reinterpret_cast<const float4*>(&W[(k0 + bkr) * 256 + col0 + bj4]);
        As[sr][sk4 + 0] = a4.x; As[sr][sk4 + 1] = a4.y; As[sr][sk4 + 2] = a4.z; As[sr][sk4 + 3] = a4.w;
        Bs[bkr][bj4 + 0] = b4.x; Bs[bkr][bj4 + 1] = b4.y; Bs[bkr][bj4 + 2] = b4.z; Bs[bkr][bj4 + 3] = b4.w;
        __syncthreads();
        #pragma unroll
        for (int k = 0; k < 16; ++k) {
            float a[4], bbv[4];
            #pragma unroll
            for (int i = 0; i < 4; ++i) a[i] = As[tr * 4 + i][k];
            #pragma unroll
            for (int j = 0; j < 4; ++j) bbv[j] = Bs[k][tc * 4 + j];
            #pragma unroll
            for (int i = 0; i < 4; ++i)
                #pragma unroll
                for (int j = 0; j < 4; ++j)
                    acc[i][j] = fmaf(a[i], bbv[j], acc[i][j]);
        }
        __syncthreads();
    }
    #pragma unroll
    for (int i = 0; i < 4; ++i) {
        const int r = row0 + tr * 4 + i;
        #pragma unroll
        for (int j = 0; j < 4; ++j) {
            const int cj = col0 + tc * 4 + j;
            out[r * 256 + cj] = acc[i][j] + bias[cj];
        }
    }
}

// ---------------------------------------------------------------------------
// K2: qW[b,n,h,d] = sum_c qp[b*256+n][h*64+c] * Wqk[d][h*64+c]
// per-head GEMM (M=512 rows, N=256 d, K=64 c), B transposed.
// ---------------------------------------------------------------------------
__global__ __launch_bounds__(256) void qw_gemm(
    const float* __restrict__ qp, const float* __restrict__ Wqk, float* __restrict__ qW)
{
    const int h    = blockIdx.z;
    const int row0 = blockIdx.x * 64;
    const int d0   = blockIdx.y * 64;
    __shared__ float As[64][17];
    __shared__ float Bs[16][68];
    const int t  = threadIdx.x;
    const int tr = t >> 4, tc = t & 15;
    float acc[4][4] = {};
    const int sr = t >> 2, sc4 = (t & 3) << 2;

    for (int k0 = 0; k0 < 64; k0 += 16) {
        float4 a4 = *reinterpret_cast<const float4*>(&qp[(row0 + sr) * 256 + h * 64 + k0 + sc4]);
        float4 b4 = *reinterpret_cast<const float4*>(&Wqk[(d0 + sr) * 256 + h * 64 + k0 + sc4]);
        As[sr][sc4 + 0] = a4.x; As[sr][sc4 + 1] = a4.y; As[sr][sc4 + 2] = a4.z; As[sr][sc4 + 3] = a4.w;
        Bs[sc4 + 0][sr] = b4.x; Bs[sc4 + 1][sr] = b4.y; Bs[sc4 + 2][sr] = b4.z; Bs[sc4 + 3][sr] = b4.w;
        __syncthreads();
        #pragma unroll
        for (int k = 0; k < 16; ++k) {
            float a[4], bbv[4];
            #pragma unroll
            for (int i = 0; i < 4; ++i) a[i] = As[tr * 4 + i][k];
            #pragma unroll
            for (int j = 0; j < 4; ++j) bbv[j] = Bs[k][tc * 4 + j];
            #pragma unroll
            for (int i = 0; i < 4; ++i)
                #pragma unroll
                for (int j = 0; j < 4; ++j)
                    acc[i][j] = fmaf(a[i], bbv[j], acc[i][j]);
        }
        __syncthreads();
    }
    #pragma unroll
    for (int i = 0; i < 4; ++i)
        #pragma unroll
        for (int j = 0; j < 4; ++j)
            qW[((row0 + tr * 4 + i) * 4 + h) * 256 + d0 + tc * 4 + j] = acc[i][j];
}

__device__ __forceinline__ float dot4acc(float4 e, float4 w, float s) {
    s = fmaf(e.x, w.x, s); s = fmaf(e.y, w.y, s);
    s = fmaf(e.z, w.z, s); s = fmaf(e.w, w.w, s);
    return s;
}

// ---------------------------------------------------------------------------
// K3: per (b,n): stream qk_embeds[b,n] (256KB), pair scores + q.k + softmax.
// block = 256 threads = 4 waves. Pair phase: wave w -> m in [64w,64w+64),
// lane owns d-quarter slice, 16-lane shuffle reduce. Softmax phase: wave w = head w.
// ---------------------------------------------------------------------------
__global__ __launch_bounds__(256) void score_softmax(
    const float* __restrict__ qk_emb, const float* __restrict__ qkvp,
    const float* __restrict__ qW, float* __restrict__ attn_out)
{
    const int bn = blockIdx.x;
    const int b  = bn >> 8, n = bn & 255;
    const int t  = threadIdx.x;
    const int w  = t >> 6, l = t & 63;
    __shared__ float S[4][256];
    __shared__ float qrow[256];
    qrow[t] = qkvp[bn * 256 + t];

    const int lq = l & 15;   // d-slice within group
    const int lr = l >> 4;   // row within group of 4

    float4 Wreg[4][4];
    #pragma unroll
    for (int h = 0; h < 4; ++h)
        #pragma unroll
        for (int dc = 0; dc < 4; ++dc)
            Wreg[h][dc] = *reinterpret_cast<const float4*>(&qW[(bn * 4 + h) * 256 + dc * 64 + lq * 4]);

    for (int g = 0; g < 16; ++g) {
        const int m = w * 64 + g * 4 + lr;
        const float* er = qk_emb + (size_t)(bn * 256 + m) * 256 + lq * 4;
        const float4 e0 = *reinterpret_cast<const float4*>(er);
        const float4 e1 = *reinterpret_cast<const float4*>(er + 64);
        const float4 e2 = *reinterpret_cast<const float4*>(er + 128);
        const float4 e3 = *reinterpret_cast<const float4*>(er + 192);
        float a[4];
        #pragma unroll
        for (int h = 0; h < 4; ++h) {
            float s = 0.f;
            s = dot4acc(e0, Wreg[h][0], s);
            s = dot4acc(e1, Wreg[h][1], s);
            s = dot4acc(e2, Wreg[h][2], s);
            s = dot4acc(e3, Wreg[h][3], s);
            a[h] = s;
        }
        #pragma unroll
        for (int h = 0; h < 4; ++h) {
            a[h] += __shfl_xor(a[h], 1);
            a[h] += __shfl_xor(a[h], 2);
            a[h] += __shfl_xor(a[h], 4);
            a[h] += __shfl_xor(a[h], 8);
        }
        if (lq == 0) {
            #pragma unroll
            for (int h = 0; h < 4; ++h) S[h][m] = a[h];
        }
    }
    __syncthreads();

    // wave w = head w: add q.k, softmax over m
    float sv[4];
    #pragma unroll
    for (int rep = 0; rep < 4; ++rep) {
        const int m = l + rep * 64;
        const float* kr = qkvp + (512 + b * 256 + m) * 256 + w * 64;
        float dot = 0.f;
        #pragma unroll 8
        for (int c = 0; c < 64; ++c) dot = fmaf(qrow[w * 64 + c], kr[c], dot);
        sv[rep] = (S[w][m] + dot) * 0.125f;
    }
    float mx = fmaxf(fmaxf(sv[0], sv[1]), fmaxf(sv[2], sv[3]));
    #pragma unroll
    for (int mask = 32; mask >= 1; mask >>= 1) mx = fmaxf(mx, __shfl_xor(mx, mask));
    float sum = 0.f;
    #pragma unroll
    for (int rep = 0; rep < 4; ++rep) { sv[rep] = __expf(sv[rep] - mx); sum += sv[rep]; }
    #pragma unroll
    for (int mask = 32; mask >= 1; mask >>= 1) sum += __shfl_xor(sum, mask);
    const float inv = 1.f / sum;
    float* ao = attn_out + (size_t)((b * 4 + w) * 256 + n) * 256;
    #pragma unroll
    for (int rep = 0; rep < 4; ++rep) ao[l + rep * 64] = sv[rep] * inv;
}

// ---------------------------------------------------------------------------
// K4: per (b,n): A[h][d] = sum_m attn[h][m]*qv_emb[b,n,m,d]  (stream 256KB),
// then hidden = attn@v + A@Wqv + bqv.
// ---------------------------------------------------------------------------
__global__ __launch_bounds__(256) void out_kernel(
    const float* __restrict__ qv_emb, const float* __restrict__ qkvp,
    const float* __restrict__ Wqv, const float* __restrict__ bqv,
    const float* __restrict__ attn_in, float* __restrict__ hidden)
{
    const int bn = blockIdx.x;
    const int b  = bn >> 8, n = bn & 255;
    const int t  = threadIdx.x;
    const int w  = t >> 6, l = t & 63;
    __shared__ float attn_s[4][256];
    __shared__ float Apart[4][4][256];
    __shared__ float Afull[4][256];

    #pragma unroll
    for (int i = 0; i < 4; ++i) {
        const int idx = t + i * 256;
        const int h = idx >> 8, m = idx & 255;
        attn_s[h][m] = attn_in[(size_t)((b * 4 + h) * 256 + n) * 256 + m];
    }
    __syncthreads();

    float4 acc[4];
    #pragma unroll
    for (int h = 0; h < 4; ++h) acc[h] = make_float4(0.f, 0.f, 0.f, 0.f);

    for (int mm = 0; mm < 64; ++mm) {
        const int m = w * 64 + mm;
        const float4 e = *reinterpret_cast<const float4*>(&qv_emb[(size_t)(bn * 256 + m) * 256 + l * 4]);
        #pragma unroll
        for (int h = 0; h < 4; ++h) {
            const float a = attn_s[h][m];
            acc[h].x = fmaf(a, e.x, acc[h].x);
            acc[h].y = fmaf(a, e.y, acc[h].y);
            acc[h].z = fmaf(a, e.z, acc[h].z);
            acc[h].w = fmaf(a, e.w, acc[h].w);
        }
    }
    #pragma unroll
    for (int h = 0; h < 4; ++h)
        *reinterpret_cast<float4*>(&Apart[w][h][l * 4]) = acc[h];
    __syncthreads();
    #pragma unroll
    for (int i = 0; i < 4; ++i) {
        const int idx = t + i * 256;
        const int h = idx >> 8, d = idx & 255;
        Afull[h][d] = Apart[0][h][d] + Apart[1][h][d] + Apart[2][h][d] + Apart[3][h][d];
    }
    __syncthreads();

    float hv = bqv[w * 64 + l];
    const float* vr = qkvp + (size_t)(1024 + b * 256) * 256 + w * 64 + l;
    #pragma unroll 8
    for (int m = 0; m < 256; ++m) hv = fmaf(attn_s[w][m], vr[m * 256], hv);
    const float* wc = Wqv + w * 64 + l;
    #pragma unroll 8
    for (int d = 0; d < 256; ++d) hv = fmaf(Afull[w][d], wc[d * 256], hv);

    hidden[(size_t)bn * 256 + w * 64 + l] = hv;
}

extern "C" void kernel_launch(void* const* d_in, const int* in_sizes, int n_in,
                              void* d_out, int out_size, void* d_ws, size_t ws_size,
                              hipStream_t stream) {
    (void)in_sizes; (void)n_in; (void)out_size; (void)ws_size;
    const float* q_tok  = (const float*)d_in[0];
    const float* k_tok  = (const float*)d_in[1];
    const float* v_tok  = (const float*)d_in[2];
    const float* qk_emb = (const float*)d_in[3];
    const float* qv_emb = (const float*)d_in[4];
    const float* Wq  = (const float*)d_in[5];   const float* bq  = (const float*)d_in[6];
    const float* Wk  = (const float*)d_in[7];   const float* bk  = (const float*)d_in[8];
    const float* Wv  = (const float*)d_in[9];   const float* bv  = (const float*)d_in[10];
    const float* Wqk = (const float*)d_in[11];  /* bqk (d_in[12]) is softmax-invariant */
    const float* Wqv = (const float*)d_in[13];  const float* bqv = (const float*)d_in[14];

    float* ws   = (float*)d_ws;
    float* qkvp = ws;                  // 1536*256 floats: q rows 0..511, k 512..1023, v 1024..1535
    float* qW   = ws + 1536 * 256;     // 512*1024 floats: [b*256+n][h][d]

    float* hidden = (float*)d_out;                       // (B,N,C)
    float* attn   = (float*)d_out + BB * NN * CC;        // (B,H,N,M)

    proj_gemm   <<<dim3(24, 4),   256, 0, stream>>>(q_tok, k_tok, v_tok, Wq, bq, Wk, bk, Wv, bv, qkvp);
    qw_gemm     <<<dim3(8, 4, 4), 256, 0, stream>>>(qkvp, Wqk, qW);
    score_softmax<<<512,          256, 0, stream>>>(qk_emb, qkvp, qW, attn);
    out_kernel  <<<512,           256, 0, stream>>>(qv_emb, qkvp, Wqv, bqv, attn, hidden);
}

// Round 3
// 108.508 us; speedup vs baseline: 1.0086x; 1.0086x over previous
//
#include <hip/hip_runtime.h>

#define BB 2
#define NN 256
#define CC 256

// ---------------------------------------------------------------------------
// K1: fused q/k/v projections.  rows 0..511 = q (B*N), 512..1023 = k, 1024..1535 = v
// ---------------------------------------------------------------------------
__global__ __launch_bounds__(256) void proj_gemm(
    const float* __restrict__ q_tok, const float* __restrict__ k_tok, const float* __restrict__ v_tok,
    const float* __restrict__ Wq, const float* __restrict__ bq,
    const float* __restrict__ Wk, const float* __restrict__ bk,
    const float* __restrict__ Wv, const float* __restrict__ bv,
    float* __restrict__ out)
{
    const int row0 = blockIdx.x * 64;
    const int col0 = blockIdx.y * 64;
    const int seg  = row0 >> 9;
    const float* A    = seg == 0 ? q_tok : (seg == 1 ? k_tok : v_tok);
    const float* W    = seg == 0 ? Wq    : (seg == 1 ? Wk    : Wv);
    const float* bias = seg == 0 ? bq    : (seg == 1 ? bk    : bv);
    const int ar0 = row0 & 511;

    __shared__ float As[64][17];
    __shared__ float Bs[16][68];
    const int t  = threadIdx.x;
    const int tr = t >> 4, tc = t & 15;
    float acc[4][4] = {};

    const int sr  = t >> 2, sk4 = (t & 3) << 2;
    const int bkr = t >> 4, bj4 = (t & 15) << 2;

    for (int k0 = 0; k0 < 256; k0 += 16) {
        float4 a4 = *reinterpret_cast<const float4*>(&A[(ar0 + sr) * 256 + k0 + sk4]);
        float4 b4 = *reinterpret_cast<const float4*>(&W[(k0 + bkr) * 256 + col0 + bj4]);
        As[sr][sk4 + 0] = a4.x; As[sr][sk4 + 1] = a4.y; As[sr][sk4 + 2] = a4.z; As[sr][sk4 + 3] = a4.w;
        Bs[bkr][bj4 + 0] = b4.x; Bs[bkr][bj4 + 1] = b4.y; Bs[bkr][bj4 + 2] = b4.z; Bs[bkr][bj4 + 3] = b4.w;
        __syncthreads();
        #pragma unroll
        for (int k = 0; k < 16; ++k) {
            float a[4], bbv[4];
            #pragma unroll
            for (int i = 0; i < 4; ++i) a[i] = As[tr * 4 + i][k];
            #pragma unroll
            for (int j = 0; j < 4; ++j) bbv[j] = Bs[k][tc * 4 + j];
            #pragma unroll
            for (int i = 0; i < 4; ++i)
                #pragma unroll
                for (int j = 0; j < 4; ++j)
                    acc[i][j] = fmaf(a[i], bbv[j], acc[i][j]);
        }
        __syncthreads();
    }
    #pragma unroll
    for (int i = 0; i < 4; ++i) {
        const int r = row0 + tr * 4 + i;
        #pragma unroll
        for (int j = 0; j < 4; ++j) {
            const int cj = col0 + tc * 4 + j;
            out[r * 256 + cj] = acc[i][j] + bias[cj];
        }
    }
}

// ---------------------------------------------------------------------------
// K2: qW[bn][h][d] = sum_c qp[bn][h*64+c] * Wqk[d][h*64+c]
// ---------------------------------------------------------------------------
__global__ __launch_bounds__(256) void qw_gemm(
    const float* __restrict__ qp, const float* __restrict__ Wqk, float* __restrict__ qW)
{
    const int h    = blockIdx.z;
    const int row0 = blockIdx.x * 64;
    const int d0   = blockIdx.y * 64;
    __shared__ float As[64][17];
    __shared__ float Bs[16][68];
    const int t  = threadIdx.x;
    const int tr = t >> 4, tc = t & 15;
    float acc[4][4] = {};
    const int sr = t >> 2, sc4 = (t & 3) << 2;

    for (int k0 = 0; k0 < 64; k0 += 16) {
        float4 a4 = *reinterpret_cast<const float4*>(&qp[(row0 + sr) * 256 + h * 64 + k0 + sc4]);
        float4 b4 = *reinterpret_cast<const float4*>(&Wqk[(d0 + sr) * 256 + h * 64 + k0 + sc4]);
        As[sr][sc4 + 0] = a4.x; As[sr][sc4 + 1] = a4.y; As[sr][sc4 + 2] = a4.z; As[sr][sc4 + 3] = a4.w;
        Bs[sc4 + 0][sr] = b4.x; Bs[sc4 + 1][sr] = b4.y; Bs[sc4 + 2][sr] = b4.z; Bs[sc4 + 3][sr] = b4.w;
        __syncthreads();
        #pragma unroll
        for (int k = 0; k < 16; ++k) {
            float a[4], bbv[4];
            #pragma unroll
            for (int i = 0; i < 4; ++i) a[i] = As[tr * 4 + i][k];
            #pragma unroll
            for (int j = 0; j < 4; ++j) bbv[j] = Bs[k][tc * 4 + j];
            #pragma unroll
            for (int i = 0; i < 4; ++i)
                #pragma unroll
                for (int j = 0; j < 4; ++j)
                    acc[i][j] = fmaf(a[i], bbv[j], acc[i][j]);
        }
        __syncthreads();
    }
    #pragma unroll
    for (int i = 0; i < 4; ++i)
        #pragma unroll
        for (int j = 0; j < 4; ++j)
            qW[((row0 + tr * 4 + i) * 4 + h) * 256 + d0 + tc * 4 + j] = acc[i][j];
}

__device__ __forceinline__ float dot4acc(float4 e, float4 w, float s) {
    s = fmaf(e.x, w.x, s); s = fmaf(e.y, w.y, s);
    s = fmaf(e.z, w.z, s); s = fmaf(e.w, w.w, s);
    return s;
}

// ---------------------------------------------------------------------------
// K3: per (b,n), 1024 threads (16 waves). Wave w handles m in [16w,16w+16).
// Lane split: lq = l&15 owns d-slice, lr = l>>4 owns row-of-4.
// Then q.k + softmax with thread -> (h = w>>2, m = (w&3)*64 + l).
// ---------------------------------------------------------------------------
__global__ __launch_bounds__(1024) void score_softmax(
    const float* __restrict__ qk_emb, const float* __restrict__ qkvp,
    const float* __restrict__ qW, float* __restrict__ attn_out)
{
    const int bn = blockIdx.x;
    const int b  = bn >> 8, n = bn & 255;
    const int t  = threadIdx.x;
    const int w  = t >> 6, l = t & 63;
    __shared__ float S[4][256];
    __shared__ float qWs[4][256];
    __shared__ float qrow[256];
    __shared__ float redm[16];
    __shared__ float reds[16];

    if (t < 256) {
        qrow[t] = qkvp[bn * 256 + t];
        // qW layout [bn][h][d]: thread t -> h = t>>6, d = (t&63)*4
        *reinterpret_cast<float4*>(&qWs[t >> 6][(t & 63) * 4]) =
            *reinterpret_cast<const float4*>(&qW[bn * 1024 + t * 4]);
    }
    __syncthreads();

    const int lq = l & 15, lr = l >> 4;

    #pragma unroll
    for (int g = 0; g < 4; ++g) {
        const int m = w * 16 + g * 4 + lr;
        const float* er = qk_emb + (size_t)(bn * 256 + m) * 256 + lq * 4;
        const float4 e0 = *reinterpret_cast<const float4*>(er);
        const float4 e1 = *reinterpret_cast<const float4*>(er + 64);
        const float4 e2 = *reinterpret_cast<const float4*>(er + 128);
        const float4 e3 = *reinterpret_cast<const float4*>(er + 192);
        float a[4];
        #pragma unroll
        for (int h = 0; h < 4; ++h) {
            float s = 0.f;
            s = dot4acc(e0, *reinterpret_cast<const float4*>(&qWs[h][lq * 4]),       s);
            s = dot4acc(e1, *reinterpret_cast<const float4*>(&qWs[h][64 + lq * 4]),  s);
            s = dot4acc(e2, *reinterpret_cast<const float4*>(&qWs[h][128 + lq * 4]), s);
            s = dot4acc(e3, *reinterpret_cast<const float4*>(&qWs[h][192 + lq * 4]), s);
            a[h] = s;
        }
        #pragma unroll
        for (int h = 0; h < 4; ++h) {
            a[h] += __shfl_xor(a[h], 1);
            a[h] += __shfl_xor(a[h], 2);
            a[h] += __shfl_xor(a[h], 4);
            a[h] += __shfl_xor(a[h], 8);
        }
        if (lq == 0) {
            #pragma unroll
            for (int h = 0; h < 4; ++h) S[h][m] = a[h];
        }
    }
    __syncthreads();

    // phase B: one thread per (h, m)
    const int h = w >> 2;
    const int m = (w & 3) * 64 + l;
    const float* kr = qkvp + (size_t)(512 + b * 256 + m) * 256 + h * 64;
    float dot = 0.f;
    #pragma unroll 8
    for (int c = 0; c < 64; ++c) dot = fmaf(qrow[h * 64 + c], kr[c], dot);
    float sv = (S[h][m] + dot) * 0.125f;

    float mx = sv;
    #pragma unroll
    for (int mask = 32; mask >= 1; mask >>= 1) mx = fmaxf(mx, __shfl_xor(mx, mask));
    if (l == 0) redm[w] = mx;
    __syncthreads();
    mx = fmaxf(fmaxf(redm[h * 4 + 0], redm[h * 4 + 1]), fmaxf(redm[h * 4 + 2], redm[h * 4 + 3]));
    const float ex = __expf(sv - mx);
    float sum = ex;
    #pragma unroll
    for (int mask = 32; mask >= 1; mask >>= 1) sum += __shfl_xor(sum, mask);
    if (l == 0) reds[w] = sum;
    __syncthreads();
    const float stot = reds[h * 4 + 0] + reds[h * 4 + 1] + reds[h * 4 + 2] + reds[h * 4 + 3];
    attn_out[(size_t)((b * 4 + h) * 256 + n) * 256 + m] = ex / stot;
}

// ---------------------------------------------------------------------------
// K4: per (b,n), 1024 threads. Wave w accumulates A over m in [16w,16w+16),
// lane owns d-slice l*4..l*4+3. Then hidden = attn@v + A@Wqv + bqv with
// 4-way split over the contraction dims.
// ---------------------------------------------------------------------------
__global__ __launch_bounds__(1024) void out_kernel(
    const float* __restrict__ qv_emb, const float* __restrict__ qkvp,
    const float* __restrict__ Wqv, const float* __restrict__ bqv,
    const float* __restrict__ attn_in, float* __restrict__ hidden)
{
    const int bn = blockIdx.x;
    const int b  = bn >> 8, n = bn & 255;
    const int t  = threadIdx.x;
    const int w  = t >> 6, l = t & 63;
    __shared__ float attn_s[4][256];
    __shared__ float Apart[16][4][256];
    __shared__ float Afull[4][256];
    __shared__ float pr[4][256];

    attn_s[t >> 8][t & 255] = attn_in[(size_t)((b * 4 + (t >> 8)) * 256 + n) * 256 + (t & 255)];
    __syncthreads();

    float4 acc[4];
    #pragma unroll
    for (int h = 0; h < 4; ++h) acc[h] = make_float4(0.f, 0.f, 0.f, 0.f);

    #pragma unroll
    for (int mm = 0; mm < 16; mm += 4) {
        float4 e[4];
        #pragma unroll
        for (int j = 0; j < 4; ++j)
            e[j] = *reinterpret_cast<const float4*>(
                &qv_emb[(size_t)(bn * 256 + w * 16 + mm + j) * 256 + l * 4]);
        #pragma unroll
        for (int j = 0; j < 4; ++j) {
            const int m = w * 16 + mm + j;
            #pragma unroll
            for (int h = 0; h < 4; ++h) {
                const float a = attn_s[h][m];
                acc[h].x = fmaf(a, e[j].x, acc[h].x);
                acc[h].y = fmaf(a, e[j].y, acc[h].y);
                acc[h].z = fmaf(a, e[j].z, acc[h].z);
                acc[h].w = fmaf(a, e[j].w, acc[h].w);
            }
        }
    }
    #pragma unroll
    for (int h = 0; h < 4; ++h)
        *reinterpret_cast<float4*>(&Apart[w][h][l * 4]) = acc[h];
    __syncthreads();

    {
        const int h = t >> 8, d = t & 255;
        float s = 0.f;
        #pragma unroll
        for (int i = 0; i < 16; ++i) s += Apart[i][h][d];
        Afull[h][d] = s;
    }
    __syncthreads();

    // phase 2: c = t&255, quarter qr = t>>8, h = c>>6
    const int c  = t & 255;
    const int qr = t >> 8;
    const int h2 = c >> 6;
    float hv = 0.f;
    const float* vcol = qkvp + (size_t)(1024 + b * 256 + qr * 64) * 256 + c;
    #pragma unroll 8
    for (int mm = 0; mm < 64; ++mm) hv = fmaf(attn_s[h2][qr * 64 + mm], vcol[mm * 256], hv);
    const float* wcol = Wqv + (size_t)(qr * 64) * 256 + c;
    #pragma unroll 8
    for (int dd = 0; dd < 64; ++dd) hv = fmaf(Afull[h2][qr * 64 + dd], wcol[dd * 256], hv);
    pr[qr][c] = hv;
    __syncthreads();

    if (t < 256)
        hidden[(size_t)bn * 256 + t] = pr[0][t] + pr[1][t] + pr[2][t] + pr[3][t] + bqv[t];
}

extern "C" void kernel_launch(void* const* d_in, const int* in_sizes, int n_in,
                              void* d_out, int out_size, void* d_ws, size_t ws_size,
                              hipStream_t stream) {
    (void)in_sizes; (void)n_in; (void)out_size; (void)ws_size;
    const float* q_tok  = (const float*)d_in[0];
    const float* k_tok  = (const float*)d_in[1];
    const float* v_tok  = (const float*)d_in[2];
    const float* qk_emb = (const float*)d_in[3];
    const float* qv_emb = (const float*)d_in[4];
    const float* Wq  = (const float*)d_in[5];   const float* bq  = (const float*)d_in[6];
    const float* Wk  = (const float*)d_in[7];   const float* bk  = (const float*)d_in[8];
    const float* Wv  = (const float*)d_in[9];   const float* bv  = (const float*)d_in[10];
    const float* Wqk = (const float*)d_in[11];  /* bqk softmax-invariant */
    const float* Wqv = (const float*)d_in[13];  const float* bqv = (const float*)d_in[14];

    float* ws   = (float*)d_ws;
    float* qkvp = ws;                  // 1536*256
    float* qW   = ws + 1536 * 256;     // 512*1024  [bn][h][d]

    float* hidden = (float*)d_out;
    float* attn   = (float*)d_out + BB * NN * CC;

    proj_gemm    <<<dim3(24, 4),   256,  0, stream>>>(q_tok, k_tok, v_tok, Wq, bq, Wk, bk, Wv, bv, qkvp);
    qw_gemm      <<<dim3(8, 4, 4), 256,  0, stream>>>(qkvp, Wqk, qW);
    score_softmax<<<512,           1024, 0, stream>>>(qk_emb, qkvp, qW, attn);
    out_kernel   <<<512,           1024, 0, stream>>>(qv_emb, qkvp, Wqv, bqv, attn, hidden);
}